// Round 1
// baseline (3122.861 us; speedup 1.0000x reference)
//
#include <hip/hip_runtime.h>
#include <math.h>

namespace {
constexpr int   NG    = 64;
constexpr int   GC    = NG * NG * NG;
constexpr int   BOUND = 3;
constexpr float DXf    = 1.0f / 64.0f;
constexpr float INV_DX = 64.0f;
constexpr float DTf    = 5e-4f;
constexpr double P_VOL_D = (0.5 / 64.0) * (0.5 / 64.0) * (0.5 / 64.0);
constexpr float P_MASS_F = (float)(P_VOL_D * 1000.0);
// -DT * P_VOL * 4 * INV_DX^2, computed in double then cast (matches JAX trace-time scalar)
constexpr float AFFINE_SCALE = (float)(-5e-4 * P_VOL_D * 4.0 * 64.0 * 64.0);
constexpr float D_INV  = 4.0f * 64.0f * 64.0f;   // 16384
constexpr float GRAV_Y = -9.8f;
}

// ---------------- P2G: scatter particle momentum+mass to grid ----------------
__global__ __launch_bounds__(256) void p2g_kernel(const float* __restrict__ x,
                                                  const float* __restrict__ v,
                                                  const float* __restrict__ C,
                                                  const float* __restrict__ st,
                                                  float* __restrict__ grid, int n)
{
    int p = blockIdx.x * 256 + threadIdx.x;
    if (p >= n) return;

    float xp0 = x[3*p], xp1 = x[3*p+1], xp2 = x[3*p+2];
    float t0 = xp0 * INV_DX, t1 = xp1 * INV_DX, t2 = xp2 * INV_DX;
    float b0 = floorf(t0 - 0.5f), b1 = floorf(t1 - 0.5f), b2 = floorf(t2 - 0.5f);
    int   base0 = (int)b0, base1 = (int)b1, base2 = (int)b2;
    float fx0 = t0 - b0, fx1 = t1 - b1, fx2 = t2 - b2;

    float w[3][3];
    {
        float f0 = fx0, f1 = fx1, f2 = fx2;
        w[0][0] = 0.5f*(1.5f-f0)*(1.5f-f0); w[0][1] = 0.5f*(1.5f-f1)*(1.5f-f1); w[0][2] = 0.5f*(1.5f-f2)*(1.5f-f2);
        w[1][0] = 0.75f-(f0-1.0f)*(f0-1.0f); w[1][1] = 0.75f-(f1-1.0f)*(f1-1.0f); w[1][2] = 0.75f-(f2-1.0f)*(f2-1.0f);
        w[2][0] = 0.5f*(f0-0.5f)*(f0-0.5f); w[2][1] = 0.5f*(f1-0.5f)*(f1-0.5f); w[2][2] = 0.5f*(f2-0.5f)*(f2-0.5f);
    }

    float aff[3][3];
#pragma unroll
    for (int i = 0; i < 3; ++i)
#pragma unroll
        for (int j = 0; j < 3; ++j)
            aff[i][j] = st[9*p + 3*i + j] * AFFINE_SCALE + P_MASS_F * C[9*p + 3*i + j];

    float mv0 = P_MASS_F * v[3*p], mv1 = P_MASS_F * v[3*p+1], mv2 = P_MASS_F * v[3*p+2];
    float wm = P_MASS_F;

#pragma unroll
    for (int i = 0; i < 3; ++i) {
        float dp0 = ((float)i - fx0) * DXf;
#pragma unroll
        for (int j = 0; j < 3; ++j) {
            float dp1 = ((float)j - fx1) * DXf;
            float wij = w[i][0] * w[j][1];
            // partial momentum (k-independent part)
            float m0 = mv0 + aff[0][0]*dp0 + aff[0][1]*dp1;
            float m1 = mv1 + aff[1][0]*dp0 + aff[1][1]*dp1;
            float m2 = mv2 + aff[2][0]*dp0 + aff[2][1]*dp1;
            int cellij = ((base0 + i) * NG + (base1 + j)) * NG + base2;
#pragma unroll
            for (int k = 0; k < 3; ++k) {
                float dp2 = ((float)k - fx2) * DXf;
                float wi = wij * w[k][2];
                float* cptr = grid + 4 * (cellij + k);
                atomicAdd(cptr + 0, wi * (m0 + aff[0][2]*dp2));
                atomicAdd(cptr + 1, wi * (m1 + aff[1][2]*dp2));
                atomicAdd(cptr + 2, wi * (m2 + aff[2][2]*dp2));
                atomicAdd(cptr + 3, wi * wm);
            }
        }
    }
}

// ---------------- grid: normalize, gravity, boundary ----------------
__global__ __launch_bounds__(256) void grid_kernel(float* __restrict__ grid)
{
    int g = blockIdx.x * 256 + threadIdx.x;
    if (g >= GC) return;
    float4 val = ((const float4*)grid)[g];
    float m = val.w;
    float v0 = 0.f, v1 = 0.f, v2 = 0.f;
    if (m > 0.f) {
        float mm = fmaxf(m, 1e-10f);
        v0 = val.x / mm;
        v1 = val.y / mm + DTf * GRAV_Y;
        v2 = val.z / mm;
    }
    int ci = g >> 12, cj = (g >> 6) & 63, ck = g & 63;
    if ((ci < BOUND && v0 < 0.f) || (ci >= NG - BOUND && v0 > 0.f)) v0 = 0.f;
    if ((cj < BOUND && v1 < 0.f) || (cj >= NG - BOUND && v1 > 0.f)) v1 = 0.f;
    if ((ck < BOUND && v2 < 0.f) || (ck >= NG - BOUND && v2 > 0.f)) v2 = 0.f;
    ((float4*)grid)[g] = make_float4(v0, v1, v2, m);
}

// ---------------- G2P: gather, advect, update C/F ----------------
__global__ __launch_bounds__(256) void g2p_kernel(const float* __restrict__ x,
                                                  const float* __restrict__ F,
                                                  const float* __restrict__ grid,
                                                  float* __restrict__ out_x,
                                                  float* __restrict__ out_v,
                                                  float* __restrict__ out_C,
                                                  float* __restrict__ out_F,
                                                  int n)
{
    int p = blockIdx.x * 256 + threadIdx.x;
    if (p >= n) return;

    float xp0 = x[3*p], xp1 = x[3*p+1], xp2 = x[3*p+2];
    float t0 = xp0 * INV_DX, t1 = xp1 * INV_DX, t2 = xp2 * INV_DX;
    float b0 = floorf(t0 - 0.5f), b1 = floorf(t1 - 0.5f), b2 = floorf(t2 - 0.5f);
    int   base0 = (int)b0, base1 = (int)b1, base2 = (int)b2;
    float fx0 = t0 - b0, fx1 = t1 - b1, fx2 = t2 - b2;

    float w[3][3];
    w[0][0] = 0.5f*(1.5f-fx0)*(1.5f-fx0); w[0][1] = 0.5f*(1.5f-fx1)*(1.5f-fx1); w[0][2] = 0.5f*(1.5f-fx2)*(1.5f-fx2);
    w[1][0] = 0.75f-(fx0-1.0f)*(fx0-1.0f); w[1][1] = 0.75f-(fx1-1.0f)*(fx1-1.0f); w[1][2] = 0.75f-(fx2-1.0f)*(fx2-1.0f);
    w[2][0] = 0.5f*(fx0-0.5f)*(fx0-0.5f); w[2][1] = 0.5f*(fx1-0.5f)*(fx1-0.5f); w[2][2] = 0.5f*(fx2-0.5f)*(fx2-0.5f);

    float vn0 = 0.f, vn1 = 0.f, vn2 = 0.f;
    float Cn[3][3] = {};

#pragma unroll
    for (int i = 0; i < 3; ++i) {
        float dp0 = ((float)i - fx0) * DXf;
#pragma unroll
        for (int j = 0; j < 3; ++j) {
            float dp1 = ((float)j - fx1) * DXf;
            float wij = w[i][0] * w[j][1];
            int cellij = ((base0 + i) * NG + (base1 + j)) * NG + base2;
#pragma unroll
            for (int k = 0; k < 3; ++k) {
                float dp2 = ((float)k - fx2) * DXf;
                float wi = wij * w[k][2];
                float4 gv = ((const float4*)grid)[cellij + k];
                vn0 += wi * gv.x; vn1 += wi * gv.y; vn2 += wi * gv.z;
                float wx = wi * gv.x, wy = wi * gv.y, wz = wi * gv.z;
                Cn[0][0] += wx * dp0; Cn[0][1] += wx * dp1; Cn[0][2] += wx * dp2;
                Cn[1][0] += wy * dp0; Cn[1][1] += wy * dp1; Cn[1][2] += wy * dp2;
                Cn[2][0] += wz * dp0; Cn[2][1] += wz * dp1; Cn[2][2] += wz * dp2;
            }
        }
    }

#pragma unroll
    for (int i = 0; i < 3; ++i)
#pragma unroll
        for (int j = 0; j < 3; ++j)
            Cn[i][j] *= D_INV;

    // outputs
    out_x[3*p]   = xp0 + DTf * vn0;
    out_x[3*p+1] = xp1 + DTf * vn1;
    out_x[3*p+2] = xp2 + DTf * vn2;
    out_v[3*p]   = vn0; out_v[3*p+1] = vn1; out_v[3*p+2] = vn2;

    float Fp[3][3];
#pragma unroll
    for (int i = 0; i < 3; ++i)
#pragma unroll
        for (int j = 0; j < 3; ++j)
            Fp[i][j] = F[9*p + 3*i + j];

#pragma unroll
    for (int i = 0; i < 3; ++i) {
#pragma unroll
        for (int k = 0; k < 3; ++k) {
            float acc = Cn[i][0]*Fp[0][k] + Cn[i][1]*Fp[1][k] + Cn[i][2]*Fp[2][k];
            out_F[9*p + 3*i + k] = Fp[i][k] + DTf * acc;
            out_C[9*p + 3*i + k] = Cn[i][k];
        }
    }
}

extern "C" void kernel_launch(void* const* d_in, const int* in_sizes, int n_in,
                              void* d_out, int out_size, void* d_ws, size_t ws_size,
                              hipStream_t stream)
{
    const float* x  = (const float*)d_in[0];
    const float* v  = (const float*)d_in[1];
    const float* C  = (const float*)d_in[2];
    const float* F  = (const float*)d_in[3];
    const float* st = (const float*)d_in[4];
    int n = in_sizes[0] / 3;

    float* grid = (float*)d_ws;                    // GC * 4 floats = 4 MiB
    float* out  = (float*)d_out;
    float* out_x = out;
    float* out_v = out + 3 * (size_t)n;
    float* out_C = out + 6 * (size_t)n;
    float* out_F = out + 15 * (size_t)n;

    hipMemsetAsync(grid, 0, (size_t)GC * 4 * sizeof(float), stream);

    int pblocks = (n + 255) / 256;
    p2g_kernel<<<pblocks, 256, 0, stream>>>(x, v, C, st, grid, n);
    grid_kernel<<<GC / 256, 256, 0, stream>>>(grid);
    g2p_kernel<<<pblocks, 256, 0, stream>>>(x, F, grid, out_x, out_v, out_C, out_F, n);
}

// Round 3
// 839.659 us; speedup vs baseline: 3.7192x; 3.7192x over previous
//
#include <hip/hip_runtime.h>
#include <math.h>

namespace {
constexpr int   NG    = 64;
constexpr int   GC    = NG * NG * NG;
constexpr int   BOUND = 3;
constexpr int   TPA   = 16;              // tiles per axis (4^3 cells per tile)
constexpr int   NT    = TPA * TPA * TPA; // 4096 tiles
constexpr float DXf    = 1.0f / 64.0f;
constexpr float INV_DX = 64.0f;
constexpr float DTf    = 5e-4f;
constexpr double P_VOL_D = (0.5 / 64.0) * (0.5 / 64.0) * (0.5 / 64.0);
constexpr float P_MASS_F = (float)(P_VOL_D * 1000.0);
constexpr float AFFINE_SCALE = (float)(-5e-4 * P_VOL_D * 4.0 * 64.0 * 64.0);
constexpr float D_INV  = 4.0f * 64.0f * 64.0f;   // 16384
constexpr float GRAV_Y = -9.8f;

__device__ __forceinline__ int tile_of(int b0, int b1, int b2) {
    return ((b0 >> 2) * TPA + (b1 >> 2)) * TPA + (b2 >> 2);
}
__device__ __forceinline__ void base_of(const float* x, int p,
                                        int& b0, int& b1, int& b2) {
    float t0 = x[3*p] * INV_DX, t1 = x[3*p+1] * INV_DX, t2 = x[3*p+2] * INV_DX;
    b0 = (int)floorf(t0 - 0.5f); b1 = (int)floorf(t1 - 0.5f); b2 = (int)floorf(t2 - 0.5f);
}

__device__ __forceinline__ void weights_of(float fx0, float fx1, float fx2, float w[3][3]) {
    w[0][0] = 0.5f*(1.5f-fx0)*(1.5f-fx0); w[0][1] = 0.5f*(1.5f-fx1)*(1.5f-fx1); w[0][2] = 0.5f*(1.5f-fx2)*(1.5f-fx2);
    w[1][0] = 0.75f-(fx0-1.0f)*(fx0-1.0f); w[1][1] = 0.75f-(fx1-1.0f)*(fx1-1.0f); w[1][2] = 0.75f-(fx2-1.0f)*(fx2-1.0f);
    w[2][0] = 0.5f*(fx0-0.5f)*(fx0-0.5f); w[2][1] = 0.5f*(fx1-0.5f)*(fx1-0.5f); w[2][2] = 0.5f*(fx2-0.5f)*(fx2-0.5f);
}
}

// ---------------- pass 1: histogram particles into tiles ----------------
__global__ __launch_bounds__(256) void count_kernel(const float* __restrict__ x,
                                                    int* __restrict__ cnt, int n)
{
    int p = blockIdx.x * 256 + threadIdx.x;
    if (p >= n) return;
    int b0, b1, b2; base_of(x, p, b0, b1, b2);
    atomicAdd(&cnt[tile_of(b0, b1, b2)], 1);
}

// ---------------- pass 2: exclusive scan over 4096 tile counts ----------------
__global__ __launch_bounds__(256) void scan_kernel(const int* __restrict__ cnt,
                                                   int* __restrict__ start,
                                                   int* __restrict__ cursor)
{
    __shared__ int partial[256];
    int tid = threadIdx.x;
    int local[16];
    int s = 0;
#pragma unroll
    for (int i = 0; i < 16; ++i) { local[i] = s; s += cnt[tid * 16 + i]; }
    partial[tid] = s;
    __syncthreads();
    for (int off = 1; off < 256; off <<= 1) {
        int v = (tid >= off) ? partial[tid - off] : 0;
        __syncthreads();
        partial[tid] += v;
        __syncthreads();
    }
    int base = (tid > 0) ? partial[tid - 1] : 0;
#pragma unroll
    for (int i = 0; i < 16; ++i) {
        int st = base + local[i];
        start[tid * 16 + i]  = st;
        cursor[tid * 16 + i] = st;
    }
}

// ---------------- pass 3: scatter particle indices into tile order ----------------
__global__ __launch_bounds__(256) void scatter_kernel(const float* __restrict__ x,
                                                      int* __restrict__ cursor,
                                                      int* __restrict__ pidx, int n)
{
    int p = blockIdx.x * 256 + threadIdx.x;
    if (p >= n) return;
    int b0, b1, b2; base_of(x, p, b0, b1, b2);
    int pos = atomicAdd(&cursor[tile_of(b0, b1, b2)], 1);
    pidx[pos] = p;
}

// ---------------- pass 4: tiled P2G with LDS aggregation ----------------
__global__ __launch_bounds__(256) void p2g_tiled(const float* __restrict__ x,
                                                 const float* __restrict__ v,
                                                 const float* __restrict__ C,
                                                 const float* __restrict__ st,
                                                 const int* __restrict__ start,
                                                 const int* __restrict__ cnt,
                                                 const int* __restrict__ pidx,
                                                 float* __restrict__ grid)
{
    int t = blockIdx.x;
    int n = cnt[t];
    if (n == 0) return;

    __shared__ float lg[6 * 6 * 6 * 4];           // 3456 B halo tile
    for (int i = threadIdx.x; i < 864; i += 256) lg[i] = 0.f;
    __syncthreads();

    int t0 = t / (TPA * TPA), t1 = (t / TPA) % TPA, t2 = t % TPA;
    int org0 = t0 * 4, org1 = t1 * 4, org2 = t2 * 4;
    int s0 = start[t];

    for (int i = threadIdx.x; i < n; i += 256) {
        int p = pidx[s0 + i];
        float xp0 = x[3*p], xp1 = x[3*p+1], xp2 = x[3*p+2];
        float u0 = xp0 * INV_DX, u1 = xp1 * INV_DX, u2 = xp2 * INV_DX;
        float b0f = floorf(u0 - 0.5f), b1f = floorf(u1 - 0.5f), b2f = floorf(u2 - 0.5f);
        int base0 = (int)b0f, base1 = (int)b1f, base2 = (int)b2f;
        float fx0 = u0 - b0f, fx1 = u1 - b1f, fx2 = u2 - b2f;

        float w[3][3];
        weights_of(fx0, fx1, fx2, w);

        float aff[3][3];
#pragma unroll
        for (int r = 0; r < 3; ++r)
#pragma unroll
            for (int c = 0; c < 3; ++c)
                aff[r][c] = st[9*p + 3*r + c] * AFFINE_SCALE + P_MASS_F * C[9*p + 3*r + c];

        float mv0 = P_MASS_F * v[3*p], mv1 = P_MASS_F * v[3*p+1], mv2 = P_MASS_F * v[3*p+2];

        int l0 = base0 - org0, l1 = base1 - org1, l2 = base2 - org2;

#pragma unroll
        for (int oi = 0; oi < 3; ++oi) {
            float dp0 = ((float)oi - fx0) * DXf;
#pragma unroll
            for (int oj = 0; oj < 3; ++oj) {
                float dp1 = ((float)oj - fx1) * DXf;
                float wij = w[oi][0] * w[oj][1];
                float m0 = mv0 + aff[0][0]*dp0 + aff[0][1]*dp1;
                float m1 = mv1 + aff[1][0]*dp0 + aff[1][1]*dp1;
                float m2 = mv2 + aff[2][0]*dp0 + aff[2][1]*dp1;
                int lij = (((l0 + oi) * 6) + (l1 + oj)) * 6 + l2;
#pragma unroll
                for (int ok = 0; ok < 3; ++ok) {
                    float dp2 = ((float)ok - fx2) * DXf;
                    float wi = wij * w[ok][2];
                    float* cptr = &lg[4 * (lij + ok)];
                    atomicAdd(cptr + 0, wi * (m0 + aff[0][2]*dp2));
                    atomicAdd(cptr + 1, wi * (m1 + aff[1][2]*dp2));
                    atomicAdd(cptr + 2, wi * (m2 + aff[2][2]*dp2));
                    atomicAdd(cptr + 3, wi * P_MASS_F);
                }
            }
        }
    }
    __syncthreads();

    // flush 6^3 halo tile to global grid
    for (int c = threadIdx.x; c < 216; c += 256) {
        int c0 = c / 36, c1 = (c / 6) % 6, c2 = c % 6;
        int g0 = org0 + c0, g1 = org1 + c1, g2 = org2 + c2;
        if (g0 >= NG || g1 >= NG || g2 >= NG) continue;
        float a0 = lg[c*4], a1 = lg[c*4+1], a2 = lg[c*4+2], a3 = lg[c*4+3];
        if (a3 == 0.f && a0 == 0.f && a1 == 0.f && a2 == 0.f) continue;
        float* gptr = grid + 4 * (((g0 * NG) + g1) * NG + g2);
        atomicAdd(gptr + 0, a0);
        atomicAdd(gptr + 1, a1);
        atomicAdd(gptr + 2, a2);
        atomicAdd(gptr + 3, a3);
    }
}

// ---------------- fallback P2G: direct global atomics (no extra workspace) ----------------
__global__ __launch_bounds__(256) void p2g_naive(const float* __restrict__ x,
                                                 const float* __restrict__ v,
                                                 const float* __restrict__ C,
                                                 const float* __restrict__ st,
                                                 float* __restrict__ grid, int n)
{
    int p = blockIdx.x * 256 + threadIdx.x;
    if (p >= n) return;

    float xp0 = x[3*p], xp1 = x[3*p+1], xp2 = x[3*p+2];
    float u0 = xp0 * INV_DX, u1 = xp1 * INV_DX, u2 = xp2 * INV_DX;
    float b0f = floorf(u0 - 0.5f), b1f = floorf(u1 - 0.5f), b2f = floorf(u2 - 0.5f);
    int base0 = (int)b0f, base1 = (int)b1f, base2 = (int)b2f;
    float fx0 = u0 - b0f, fx1 = u1 - b1f, fx2 = u2 - b2f;

    float w[3][3];
    weights_of(fx0, fx1, fx2, w);

    float aff[3][3];
#pragma unroll
    for (int i = 0; i < 3; ++i)
#pragma unroll
        for (int j = 0; j < 3; ++j)
            aff[i][j] = st[9*p + 3*i + j] * AFFINE_SCALE + P_MASS_F * C[9*p + 3*i + j];

    float mv0 = P_MASS_F * v[3*p], mv1 = P_MASS_F * v[3*p+1], mv2 = P_MASS_F * v[3*p+2];

#pragma unroll
    for (int i = 0; i < 3; ++i) {
        float dp0 = ((float)i - fx0) * DXf;
#pragma unroll
        for (int j = 0; j < 3; ++j) {
            float dp1 = ((float)j - fx1) * DXf;
            float wij = w[i][0] * w[j][1];
            float m0 = mv0 + aff[0][0]*dp0 + aff[0][1]*dp1;
            float m1 = mv1 + aff[1][0]*dp0 + aff[1][1]*dp1;
            float m2 = mv2 + aff[2][0]*dp0 + aff[2][1]*dp1;
            int cellij = ((base0 + i) * NG + (base1 + j)) * NG + base2;
#pragma unroll
            for (int k = 0; k < 3; ++k) {
                float dp2 = ((float)k - fx2) * DXf;
                float wi = wij * w[k][2];
                float* cptr = grid + 4 * (cellij + k);
                atomicAdd(cptr + 0, wi * (m0 + aff[0][2]*dp2));
                atomicAdd(cptr + 1, wi * (m1 + aff[1][2]*dp2));
                atomicAdd(cptr + 2, wi * (m2 + aff[2][2]*dp2));
                atomicAdd(cptr + 3, wi * P_MASS_F);
            }
        }
    }
}

// ---------------- grid: normalize, gravity, boundary ----------------
__global__ __launch_bounds__(256) void grid_kernel(float* __restrict__ grid)
{
    int g = blockIdx.x * 256 + threadIdx.x;
    if (g >= GC) return;
    float4 val = ((const float4*)grid)[g];
    float m = val.w;
    float v0 = 0.f, v1 = 0.f, v2 = 0.f;
    if (m > 0.f) {
        float mm = fmaxf(m, 1e-10f);
        v0 = val.x / mm;
        v1 = val.y / mm + DTf * GRAV_Y;
        v2 = val.z / mm;
    }
    int ci = g >> 12, cj = (g >> 6) & 63, ck = g & 63;
    if ((ci < BOUND && v0 < 0.f) || (ci >= NG - BOUND && v0 > 0.f)) v0 = 0.f;
    if ((cj < BOUND && v1 < 0.f) || (cj >= NG - BOUND && v1 > 0.f)) v1 = 0.f;
    if ((ck < BOUND && v2 < 0.f) || (ck >= NG - BOUND && v2 > 0.f)) v2 = 0.f;
    ((float4*)grid)[g] = make_float4(v0, v1, v2, m);
}

// ---------------- G2P: gather, advect, update C/F ----------------
__global__ __launch_bounds__(256) void g2p_kernel(const float* __restrict__ x,
                                                  const float* __restrict__ F,
                                                  const float* __restrict__ grid,
                                                  float* __restrict__ out_x,
                                                  float* __restrict__ out_v,
                                                  float* __restrict__ out_C,
                                                  float* __restrict__ out_F,
                                                  int n)
{
    int p = blockIdx.x * 256 + threadIdx.x;
    if (p >= n) return;

    float xp0 = x[3*p], xp1 = x[3*p+1], xp2 = x[3*p+2];
    float t0 = xp0 * INV_DX, t1 = xp1 * INV_DX, t2 = xp2 * INV_DX;
    float b0 = floorf(t0 - 0.5f), b1 = floorf(t1 - 0.5f), b2 = floorf(t2 - 0.5f);
    int   base0 = (int)b0, base1 = (int)b1, base2 = (int)b2;
    float fx0 = t0 - b0, fx1 = t1 - b1, fx2 = t2 - b2;

    float w[3][3];
    weights_of(fx0, fx1, fx2, w);

    float vn0 = 0.f, vn1 = 0.f, vn2 = 0.f;
    float Cn[3][3] = {};

#pragma unroll
    for (int i = 0; i < 3; ++i) {
        float dp0 = ((float)i - fx0) * DXf;
#pragma unroll
        for (int j = 0; j < 3; ++j) {
            float dp1 = ((float)j - fx1) * DXf;
            float wij = w[i][0] * w[j][1];
            int cellij = ((base0 + i) * NG + (base1 + j)) * NG + base2;
#pragma unroll
            for (int k = 0; k < 3; ++k) {
                float dp2 = ((float)k - fx2) * DXf;
                float wi = wij * w[k][2];
                float4 gv = ((const float4*)grid)[cellij + k];
                vn0 += wi * gv.x; vn1 += wi * gv.y; vn2 += wi * gv.z;
                float wx = wi * gv.x, wy = wi * gv.y, wz = wi * gv.z;
                Cn[0][0] += wx * dp0; Cn[0][1] += wx * dp1; Cn[0][2] += wx * dp2;
                Cn[1][0] += wy * dp0; Cn[1][1] += wy * dp1; Cn[1][2] += wy * dp2;
                Cn[2][0] += wz * dp0; Cn[2][1] += wz * dp1; Cn[2][2] += wz * dp2;
            }
        }
    }

#pragma unroll
    for (int i = 0; i < 3; ++i)
#pragma unroll
        for (int j = 0; j < 3; ++j)
            Cn[i][j] *= D_INV;

    out_x[3*p]   = xp0 + DTf * vn0;
    out_x[3*p+1] = xp1 + DTf * vn1;
    out_x[3*p+2] = xp2 + DTf * vn2;
    out_v[3*p]   = vn0; out_v[3*p+1] = vn1; out_v[3*p+2] = vn2;

    float Fp[3][3];
#pragma unroll
    for (int i = 0; i < 3; ++i)
#pragma unroll
        for (int j = 0; j < 3; ++j)
            Fp[i][j] = F[9*p + 3*i + j];

#pragma unroll
    for (int i = 0; i < 3; ++i) {
#pragma unroll
        for (int k = 0; k < 3; ++k) {
            float acc = Cn[i][0]*Fp[0][k] + Cn[i][1]*Fp[1][k] + Cn[i][2]*Fp[2][k];
            out_F[9*p + 3*i + k] = Fp[i][k] + DTf * acc;
            out_C[9*p + 3*i + k] = Cn[i][k];
        }
    }
}

extern "C" void kernel_launch(void* const* d_in, const int* in_sizes, int n_in,
                              void* d_out, int out_size, void* d_ws, size_t ws_size,
                              hipStream_t stream)
{
    const float* x  = (const float*)d_in[0];
    const float* v  = (const float*)d_in[1];
    const float* C  = (const float*)d_in[2];
    const float* F  = (const float*)d_in[3];
    const float* st = (const float*)d_in[4];
    int n = in_sizes[0] / 3;

    const size_t grid_bytes = (size_t)GC * 4 * sizeof(float);     // 4 MiB
    const size_t bin_bytes  = (size_t)NT * 3 * sizeof(int) + (size_t)n * sizeof(int);
    const bool   use_tiled  = ws_size >= grid_bytes + bin_bytes;

    char* ws = (char*)d_ws;
    float* grid = (float*)ws;  ws += grid_bytes;

    float* out  = (float*)d_out;
    float* out_x = out;
    float* out_v = out + 3 * (size_t)n;
    float* out_C = out + 6 * (size_t)n;
    float* out_F = out + 15 * (size_t)n;

    int pblocks = (n + 255) / 256;

    hipMemsetAsync(grid, 0, grid_bytes, stream);

    if (use_tiled) {
        int* cnt    = (int*)ws;  ws += NT * sizeof(int);
        int* tstart = (int*)ws;  ws += NT * sizeof(int);
        int* cursor = (int*)ws;  ws += NT * sizeof(int);
        int* pidx   = (int*)ws;  ws += (size_t)n * sizeof(int);

        hipMemsetAsync(cnt, 0, NT * sizeof(int), stream);
        count_kernel<<<pblocks, 256, 0, stream>>>(x, cnt, n);
        scan_kernel<<<1, 256, 0, stream>>>(cnt, tstart, cursor);
        scatter_kernel<<<pblocks, 256, 0, stream>>>(x, cursor, pidx, n);
        p2g_tiled<<<NT, 256, 0, stream>>>(x, v, C, st, tstart, cnt, pidx, grid);
    } else {
        p2g_naive<<<pblocks, 256, 0, stream>>>(x, v, C, st, grid, n);
    }

    grid_kernel<<<GC / 256, 256, 0, stream>>>(grid);
    g2p_kernel<<<pblocks, 256, 0, stream>>>(x, F, grid, out_x, out_v, out_C, out_F, n);
}